// Round 8
// baseline (65.571 us; speedup 1.0000x reference)
//
#include <hip/hip_runtime.h>

typedef unsigned long long u64;
typedef unsigned int u32;

#define W     4096
#define NT    256
#define PT    16          // elements per thread = chunk size
#define NCH   256         // chunks of 16
#define D32   32
#define WLMAX 192         // >= max segments (consecutive starts >= 33 apart -> <= 125)

__global__ __launch_bounds__(NT) void extrema_nms_seg(
    const float* __restrict__ x,
    const int*   __restrict__ dist_p,
    float*       __restrict__ out)
{
    const int sig = blockIdx.x;
    const float* xg = x + (size_t)sig * W;
    float*       og = out + (size_t)sig * W;
    const int dist = *dist_p;

    __shared__ __align__(16) float xs[W];     // 16 KB
    __shared__ __align__(16) u64  SK[W];      // 32 KB: survivors (fast) / keys (fallback)
    __shared__ u64  cmP[NCH + 4];             // padded chunk maxima: chunk c -> cmP[c+2]
    __shared__ u32  kFL2[NCH + 4];            // "killed from left-2" flag, target c -> [c+2]
    __shared__ u32  kFR2[NCH + 4];            // "killed from right-2" flag
    __shared__ u32  deadmap[W / 32];          // killed positions bitmap
    __shared__ u32  keptmap[W / 32];          // kept positions bitmap
    __shared__ u32  wsum[4];
    __shared__ int  worklist[WLMAX];          // segment start indices into SK
    __shared__ int  segend[WLMAX];            // segment end indices
    __shared__ int  nseg, NCs;
    __shared__ u64  redF[4];                  // fallback only

    const int tid  = threadIdx.x;
    const int lane = tid & 63, wid = tid >> 6;

    // ---- stage x + zero-init all bookkeeping ----
    {
        const float4* xg4 = (const float4*)xg;
        float4*       xs4 = (float4*)xs;
        #pragma unroll
        for (int v = tid; v < W / 4; v += NT) xs4[v] = xg4[v];
    }
    for (int k = tid; k < NCH + 4; k += NT) { kFL2[k] = 0; kFR2[k] = 0; }
    if (tid < W / 32) { deadmap[tid] = 0; keptmap[tid] = 0; }
    if (tid < 2) { cmP[tid] = 0ull; cmP[NCH + 2 + tid] = 0ull; }
    if (tid == 0) nseg = 0;
    __syncthreads();                                              // B1: xs ready

    if (dist == D32) {
        const int base = tid * PT;   // chunk == tid

        // ---- build extrema keys in registers (proven R6 build) ----
        // kr = (ab<<1)|1 if extremum else 0; full priority = u64 (ab<<32)|(W-1-i)
        u32 kr[PT];
        {
            const float4* xs4 = (const float4*)xs;
            const int b4 = tid * 4;
            const float4 q0 = xs4[b4], q1 = xs4[b4 + 1], q2 = xs4[b4 + 2], q3 = xs4[b4 + 3];
            float f[PT + 2];
            f[1] = q0.x; f[2] = q0.y; f[3] = q0.z; f[4] = q0.w;
            f[5] = q1.x; f[6] = q1.y; f[7] = q1.z; f[8] = q1.w;
            f[9] = q2.x; f[10] = q2.y; f[11] = q2.z; f[12] = q2.w;
            f[13] = q3.x; f[14] = q3.y; f[15] = q3.z; f[16] = q3.w;
            f[0]      = (base > 0)      ? xs[base - 1]  : __int_as_float(0x7f800000); // left=true at i=0
            f[PT + 1] = (base + PT < W) ? xs[base + PT] : q3.w;                        // right=false at i=W-1
            #pragma unroll
            for (int j = 0; j < PT; ++j) {
                const float xi = f[j + 1];
                const bool right = f[j + 2] > xi;
                const bool left  = xi <= f[j];
                const bool s     = xi <= 0.0f;
                const bool ext   = (right && left && s) || (!right && !left && !s);
                const u32 ab = __float_as_uint(xi) & 0x7fffffffu;
                kr[j] = ext ? ((ab << 1) | 1u) : 0u;
            }
        }
        // chunk argmax (leftmost on tie == higher full priority)
        u32 best = 0; int bj = 0;
        #pragma unroll
        for (int j = 0; j < PT; ++j) if (kr[j] > best) { best = kr[j]; bj = j; }
        const u64 myM = best ? (((u64)(best >> 1) << 32) | (u32)(W - 1 - (base + bj))) : 0ull;
        cmP[tid + 2] = myM;
        __syncthreads();                                          // B2: cm ready

        // ---- distance-2 push-kill scans (adjacent chunks resolved by cm compare) ----
        {   // my suffix vs argmax of chunk c+2 (they are right: tie -> I win, use >=)
            const u64 cmt = cmP[tid + 4];
            if (cmt != 0ull && best != 0u) {
                const u32 thr = ((u32)(cmt >> 32) << 1) | 1u;
                if (best >= thr) {
                    const int jr = (W - 1) - (int)(u32)cmt;
                    const int m0 = jr - D32 - base;               // in [0,15]
                    u32 kill = 0;
                    #pragma unroll
                    for (int j = 0; j < PT; ++j)
                        kill |= ((j >= m0) && (kr[j] >= thr)) ? 1u : 0u;
                    if (kill) kFL2[tid + 4] = 1;                  // target c+2
                }
            }
        }
        {   // my prefix vs argmax of chunk c-2 (they are left: tie -> they win, strict >)
            const u64 cmt = cmP[tid];
            if (cmt != 0ull && best != 0u) {
                const u32 thr = ((u32)(cmt >> 32) << 1) | 1u;
                if (best > thr) {
                    const int jl = (W - 1) - (int)(u32)cmt;
                    const int m1 = jl + D32 - base;               // in [0,15]
                    u32 kill = 0;
                    #pragma unroll
                    for (int j = 0; j < PT; ++j)
                        kill |= ((j <= m1) && (kr[j] > thr)) ? 1u : 0u;
                    if (kill) kFR2[tid] = 1;                      // target c-2
                }
            }
        }
        __syncthreads();                                          // B3: flags ready

        // ---- round-1 keepers (window maxima) + their kills ----
        const bool keep = (myM != 0ull) && (myM > cmP[tid + 1]) && (myM > cmP[tid + 3])
                       && (kFL2[tid + 2] == 0) && (kFR2[tid + 2] == 0);
        if (keep) {
            const int p = (W - 1) - (int)(u32)myM;
            atomicOr(&keptmap[p >> 5], 1u << (p & 31));
            int lo = p - D32; if (lo < 0) lo = 0;
            int hi = p + D32; if (hi > W - 1) hi = W - 1;
            const int w0 = lo >> 5, w1 = hi >> 5;
            for (int w2 = w0; w2 <= w1; ++w2) {
                const int b0 = (w2 == w0) ? (lo & 31) : 0;
                const int b1 = (w2 == w1) ? (hi & 31) : 31;
                const u32 m = (b1 == 31 ? 0xffffffffu : ((1u << (b1 + 1)) - 1u))
                              & ~((1u << b0) - 1u);
                atomicOr(&deadmap[w2], m);
            }
        }
        __syncthreads();                                          // B4: deadmap ready

        // ---- survivor compaction (position-ordered) ----
        const u32 db16 = deadmap[tid >> 1] >> ((tid & 1) * 16);
        u32 cnt = 0, sv = 0;
        #pragma unroll
        for (int j = 0; j < PT; ++j) {
            const u32 s2 = ((kr[j] != 0u) && (((db16 >> j) & 1u) == 0u)) ? 1u : 0u;
            sv |= s2 << j; cnt += s2;
        }
        u32 inc = cnt;
        #pragma unroll
        for (int off = 1; off < 64; off <<= 1) {
            const u32 n = __shfl_up(inc, off, 64);
            if (lane >= off) inc += n;
        }
        if (lane == 63) wsum[wid] = inc;
        __syncthreads();                                          // B5
        if (tid == 0) {
            u32 a = 0;
            for (int w2 = 0; w2 < 4; ++w2) { const u32 t2 = wsum[w2]; wsum[w2] = a; a += t2; }
            NCs = (int)a;
        }
        __syncthreads();                                          // B6
        u32 o2 = wsum[wid] + inc - cnt;
        #pragma unroll
        for (int j = 0; j < PT; ++j)
            if ((sv >> j) & 1u)
                SK[o2++] = ((u64)(kr[j] >> 1) << 32) | (u32)(W - 1 - (base + j));
        __syncthreads();                                          // B7: SK ready

        // ---- segment starts ----
        const int NC = NCs;
        for (int k = tid; k < NC; k += NT) {
            bool st;
            const int pk = (W - 1) - (int)(u32)SK[k];
            if (k == 0) st = true;
            else { const int pp = (W - 1) - (int)(u32)SK[k - 1]; st = (pk - pp) > D32; }
            if (st) { const int wix = atomicAdd(&nseg, 1); worklist[wix] = k; }
        }
        __syncthreads();                                          // B8: worklist ready

        // ---- segment extents (read-only pass; before any SK zeroing) ----
        const int NS = nseg;
        for (int w = tid; w < NS; w += NT) {
            const int k0 = worklist[w];
            int ke = k0;
            int pe = (W - 1) - (int)(u32)SK[ke];
            while (ke + 1 < NC) {
                const int pn = (W - 1) - (int)(u32)SK[ke + 1];
                if (pn - pe > D32) break;
                ++ke; pe = pn;
            }
            segend[w] = ke;
        }
        __syncthreads();                                          // B9: extents fixed

        // ---- resolve each independent segment serially (exact greedy) ----
        for (int w = tid; w < NS; w += NT) {
            const int k0 = worklist[w];
            const int ke = segend[w];
            for (;;) {
                u64 best2 = 0ull;
                for (int k = k0; k <= ke; ++k) { const u64 v = SK[k]; if (v > best2) best2 = v; }
                if (best2 == 0ull) break;
                const int p = (W - 1) - (int)(u32)best2;
                atomicOr(&keptmap[p >> 5], 1u << (p & 31));
                for (int k = k0; k <= ke; ++k) {
                    const u64 v = SK[k];
                    if (v != 0ull) {
                        const int pk = (W - 1) - (int)(u32)v;
                        const int d2 = pk - p;
                        if (d2 >= -D32 && d2 <= D32) SK[k] = 0ull;
                    }
                }
            }
        }
        __syncthreads();                                          // B10: keptmap final

        // ---- coalesced output ----
        {
            const u32 kb16 = keptmap[tid >> 1] >> ((tid & 1) * 16);
            float4*       og4 = (float4*)og + tid * 4;
            const float4* xs4 = (const float4*)xs + tid * 4;
            #pragma unroll
            for (int v = 0; v < 4; ++v) {
                const float4 q = xs4[v];
                float4 o;
                o.x = ((kb16 >> (4 * v + 0)) & 1u) ? q.x : 0.0f;
                o.y = ((kb16 >> (4 * v + 1)) & 1u) ? q.y : 0.0f;
                o.z = ((kb16 >> (4 * v + 2)) & 1u) ? q.z : 0.0f;
                o.w = ((kb16 >> (4 * v + 3)) & 1u) ? q.w : 0.0f;
                og4[v] = o;
            }
        }
    } else {
        // ---------- generic fallback (any dist): proven R1 serial-greedy ----------
        for (int i = tid; i < W; i += NT) og[i] = 0.0f;
        for (int i = tid; i < W; i += NT) {
            const float xi = xs[i];
            const bool right = (i < W - 1) ? (xs[i + 1] > xi) : false;
            const bool left  = (i > 0)     ? (xi <= xs[i - 1]) : true;
            const bool s = (xi <= 0.0f);
            const bool valley = right && left && s;
            const bool peak   = !right && !left && !s;
            const u32 ab = __float_as_uint(xi) & 0x7fffffffu;
            SK[i] = (valley || peak) ? (((u64)ab << 32) | (u64)(u32)(W - 1 - i)) : 0ull;
        }
        __syncthreads();

        for (;;) {
            u64 m = 0ull;
            #pragma unroll
            for (int j = 0; j < W / NT; ++j) {
                const u64 k = SK[tid + j * NT];
                if (k > m) m = k;
            }
            #pragma unroll
            for (int off = 32; off > 0; off >>= 1) {
                const u64 o = __shfl_down(m, off, 64);
                if (o > m) m = o;
            }
            if ((tid & 63) == 0) redF[tid >> 6] = m;
            __syncthreads();
            if (tid == 0) {
                u64 w0 = redF[0];
                #pragma unroll
                for (int w2 = 1; w2 < 4; ++w2) if (redF[w2] > w0) w0 = redF[w2];
                redF[0] = w0;
            }
            __syncthreads();
            const u64 win = redF[0];
            if (win == 0ull) break;

            const int p = (W - 1) - (int)(win & 0xffffffffu);
            if (tid == 0) og[p] = xs[p];

            int lo = p - dist; lo = lo < 0 ? 0 : lo;
            int hi = p + dist; hi = hi > (W - 1) ? (W - 1) : hi;
            for (int j = lo + tid; j <= hi; j += NT) SK[j] = 0ull;
            __syncthreads();
        }
    }
}

extern "C" void kernel_launch(void* const* d_in, const int* in_sizes, int n_in,
                              void* d_out, int out_size, void* d_ws, size_t ws_size,
                              hipStream_t stream) {
    const float* x      = (const float*)d_in[0];
    const int*   dist_p = (const int*)d_in[1];
    float*       out    = (float*)d_out;
    const int nsig = in_sizes[0] / W;   // 128 signals of length 4096
    hipLaunchKernelGGL(extrema_nms_seg, dim3(nsig), dim3(NT), 0, stream,
                       x, dist_p, out);
}

// Round 9
// 17.483 us; speedup vs baseline: 3.7506x; 3.7506x over previous
//
#include <hip/hip_runtime.h>

typedef unsigned long long u64;
typedef unsigned int u32;

#define W    4096
#define NT   128
#define CH   32          // elements per thread = chunk size = dist
#define NCH  128
#define D32  32
#define PSTR 33          // padded row stride (bank-conflict-free publish)
#define PSH  ((NCH + 4) * PSTR)

// PFX/SFX rows padded by 2 chunks each side (rows c=-2,-1,NCH,NCH+1 stay 0)
#define PFXI(c, o) (((c) + 2) * PSTR + (o))
#define SFXI(c, o) (PSH + ((c) + 2) * PSTR + (o))

__global__ __launch_bounds__(NT) void extrema_nms_ps(
    const float* __restrict__ x,
    const int*   __restrict__ dist_p,
    float*       __restrict__ out)
{
    const int sig = blockIdx.x;
    const float* xg = x + (size_t)sig * W;
    float*       og = out + (size_t)sig * W;
    const int dist = *dist_p;

    __shared__ __align__(16) float xs[W];        // 16 KB
    __shared__ __align__(16) u64   HMb[NCH + 4]; // chunk candidates, 2-padded
    __shared__ __align__(16) u32   PS[2 * PSH];  // PFX then SFX (34.8 KB; >=32KB for fallback SK)
    __shared__ int LF;                           // round-stamped live flag

    const int tid = threadIdx.x;

    // ---- stage x (coalesced float4) + zero pads ----
    {
        const float4* xg4 = (const float4*)xg;
        float4*       xs4 = (float4*)xs;
        #pragma unroll
        for (int v = tid; v < W / 4; v += NT) xs4[v] = xg4[v];
    }
    for (int k = tid; k < 4 * PSTR; k += NT) {   // zero the 4 pad rows of both arrays
        const int rr = k / PSTR, oo = k % PSTR;
        const int row = (rr < 2) ? rr : (NCH + rr);   // rows 0,1,NCH+2,NCH+3
        PS[row * PSTR + oo] = 0u;
        PS[PSH + row * PSTR + oo] = 0u;
    }
    if (tid < 2) { HMb[tid] = 0ull; HMb[NCH + 2 + tid] = 0ull; }
    if (tid == 0) LF = 0;
    __syncthreads();

    if (dist == D32) {
        const int base = tid * CH;

        // ---- build extrema keys (u32: (ab<<1)|1, 0 = dead); ties resolved by position logic ----
        u32 kb[CH];
        {
            const float4* xs4 = (const float4*)xs;
            float f[CH + 2];
            #pragma unroll
            for (int v = 0; v < 8; ++v) {
                const float4 q = xs4[tid * 8 + v];
                f[4 * v + 1] = q.x; f[4 * v + 2] = q.y;
                f[4 * v + 3] = q.z; f[4 * v + 4] = q.w;
            }
            f[0]      = (tid > 0)      ? xs[base - 1]  : __int_as_float(0x7f800000); // left=true at i=0
            f[CH + 1] = (tid < NT - 1) ? xs[base + CH] : f[CH];                       // right=false at i=W-1
            #pragma unroll
            for (int j = 0; j < CH; ++j) {
                const float xi = f[j + 1];
                const bool right = f[j + 2] > xi;
                const bool left  = xi <= f[j];
                const bool s     = xi <= 0.0f;
                const bool ext   = (right && left && s) || (!right && !left && !s);
                const u32 ab = __float_as_uint(xi) & 0x7fffffffu;
                kb[j] = ext ? ((ab << 1) | 1u) : 0u;
            }
        }
        u32 L = 0;                    // liveness bitmask
        #pragma unroll
        for (int j = 0; j < CH; ++j) if (kb[j]) L |= (1u << j);
        u32 best = 0; int bo = 0;     // chunk candidate (leftmost max = highest priority)
        #pragma unroll
        for (int j = 0; j < CH; ++j) if (kb[j] > best) { best = kb[j]; bo = j; }

        // publish current chunk state: HM + live prefix/suffix maxima
        #define PUBLISH()                                                      \
        do {                                                                   \
            u32 m_ = 0;                                                        \
            _Pragma("unroll")                                                  \
            for (int j = 0; j < CH; ++j) {                                     \
                const u32 kj = ((L >> j) & 1u) ? kb[j] : 0u;                   \
                m_ = kj > m_ ? kj : m_;                                        \
                PS[PFXI(tid, j)] = m_;                                         \
            }                                                                  \
            m_ = 0;                                                            \
            _Pragma("unroll")                                                  \
            for (int j = CH - 1; j >= 0; --j) {                                \
                const u32 kj = ((L >> j) & 1u) ? kb[j] : 0u;                   \
                m_ = kj > m_ ? kj : m_;                                        \
                PS[SFXI(tid, j)] = m_;                                         \
            }                                                                  \
            HMb[tid + 2] = best ? (((u64)best << 32) | (u32)(base + bo)) : 0ull; \
        } while (0)

        PUBLISH();
        int kpos = -1;                // kept offset in my chunk (at most one ever)

        // ---- round loop: 2 barriers, O(1) keeper tests via PFX/SFX ----
        int r = 0;
        for (;;) {
            ++r;
            const u64 bal = __ballot(best != 0u);
            if ((tid & 63) == 0 && bal) LF = r;
            __syncthreads();                                   // B1: state visible
            const int live = LF;
            const u64 hL = HMb[tid + 1];   // chunk c-1 candidate
            const u64 hR = HMb[tid + 3];   // chunk c+1 candidate
            if (live != r) break;          // uniform: nothing live anywhere

            // keeper(c): my candidate vs window maxima (2 reads, 2 compares)
            bool keep_c = false, keep_m = false, keep_p = false;
            int pL = 0, pR = 0;
            if (best) {
                const u32 sl = PS[SFXI(tid - 1, bo)];   // max over [p-32, base-1]
                const u32 pr = PS[PFXI(tid + 1, bo)];   // max over [base+32, p+32]
                keep_c = (sl < best) && (pr <= best);   // left ties win; right ties lose
            }
            const u32 ML = (u32)(hL >> 32);
            if (ML) {                      // keeper(c-1), evaluated identically by all
                pL = (int)(u32)hL;
                const int boL = pL - base + CH;         // offset in chunk c-1, [0,31]
                const u32 sl = PS[SFXI(tid - 2, boL)];
                const u32 pr = PS[PFXI(tid,     boL)];
                keep_m = (sl < ML) && (pr <= ML);
            }
            const u32 MR = (u32)(hR >> 32);
            if (MR) {                      // keeper(c+1)
                pR = (int)(u32)hR;
                const int boR = pR - base - CH;         // offset in chunk c+1, [0,31]
                const u32 sl = PS[SFXI(tid,     boR)];
                const u32 pr = PS[PFXI(tid + 2, boR)];
                keep_p = (sl < MR) && (pr <= MR);
            }
            __syncthreads();                                   // B2: read phase done

            // kills as bitmask ops (keys immutable; windows are contiguous bit ranges)
            u32 newL = L;
            if (keep_m) { const int boL = pL - base + CH; newL &= ~(0xFFFFFFFFu >> (31 - boL)); } // [0,boL]
            if (keep_p) { const int boR = pR - base - CH; newL &= ~(0xFFFFFFFFu << boR); }         // [boR,31]
            if (keep_c) { newL = 0u; kpos = bo; }       // own keeper kills whole chunk

            if (newL != L) {
                L = newL;
                if (best && !((L >> bo) & 1u)) {        // candidate died -> rescan
                    best = 0; bo = 0;
                    #pragma unroll
                    for (int j = 0; j < CH; ++j) {
                        const u32 kj = ((L >> j) & 1u) ? kb[j] : 0u;
                        if (kj > best) { best = kj; bo = j; }
                    }
                }
                PUBLISH();                               // write phase (ordered by next B1)
            }
        }

        // ---- output: each thread writes its own 128B from LDS + keeper mask ----
        {
            const float4* xs4 = (const float4*)xs;
            float4*       og4 = (float4*)og;
            #pragma unroll
            for (int v = 0; v < 8; ++v) {
                const float4 q = xs4[tid * 8 + v];
                const int j0 = 4 * v;
                float4 o;
                o.x = (kpos == j0 + 0) ? q.x : 0.0f;
                o.y = (kpos == j0 + 1) ? q.y : 0.0f;
                o.z = (kpos == j0 + 2) ? q.z : 0.0f;
                o.w = (kpos == j0 + 3) ? q.w : 0.0f;
                og4[tid * 8 + v] = o;
            }
        }
    } else {
        // ---------- generic fallback (any dist): proven serial greedy ----------
        u64* SK = (u64*)PS;              // 34.8KB >= 32KB
        for (int i = tid; i < W; i += NT) og[i] = 0.0f;
        for (int i = tid; i < W; i += NT) {
            const float xi = xs[i];
            const bool right = (i < W - 1) ? (xs[i + 1] > xi) : false;
            const bool left  = (i > 0)     ? (xi <= xs[i - 1]) : true;
            const bool s = (xi <= 0.0f);
            const bool valley = right && left && s;
            const bool peak   = !right && !left && !s;
            const u32 ab = __float_as_uint(xi) & 0x7fffffffu;
            SK[i] = (valley || peak) ? (((u64)ab << 32) | (u64)(u32)(W - 1 - i)) : 0ull;
        }
        __syncthreads();

        for (;;) {
            u64 m = 0ull;
            #pragma unroll
            for (int j = 0; j < W / NT; ++j) {
                const u64 k = SK[tid + j * NT];
                if (k > m) m = k;
            }
            #pragma unroll
            for (int off = 32; off > 0; off >>= 1) {
                const u64 o = __shfl_down(m, off, 64);
                if (o > m) m = o;
            }
            if ((tid & 63) == 0) HMb[tid >> 6] = m;
            __syncthreads();
            if (tid == 0) HMb[0] = (HMb[1] > HMb[0]) ? HMb[1] : HMb[0];
            __syncthreads();
            const u64 win = HMb[0];
            if (win == 0ull) break;

            const int p = (W - 1) - (int)(win & 0xffffffffu);
            if (tid == 0) og[p] = xs[p];

            int lo = p - dist; lo = lo < 0 ? 0 : lo;
            int hi = p + dist; hi = hi > (W - 1) ? (W - 1) : hi;
            for (int j = lo + tid; j <= hi; j += NT) SK[j] = 0ull;
            __syncthreads();
        }
    }
}

extern "C" void kernel_launch(void* const* d_in, const int* in_sizes, int n_in,
                              void* d_out, int out_size, void* d_ws, size_t ws_size,
                              hipStream_t stream) {
    const float* x      = (const float*)d_in[0];
    const int*   dist_p = (const int*)d_in[1];
    float*       out    = (float*)d_out;
    const int nsig = in_sizes[0] / W;   // 128 signals of length 4096
    hipLaunchKernelGGL(extrema_nms_ps, dim3(nsig), dim3(NT), 0, stream,
                       x, dist_p, out);
}